// Round 8
// baseline (239.271 us; speedup 1.0000x reference)
//
#include <hip/hip_runtime.h>
#include <hip/hip_bf16.h>
#include <float.h>

// Co_Attention collapsed:
//   S[b,n,m] = u_fea[b,n]·E·i_fea[b,m] + u_fea[b,n]·a + g·i_fea[b,m] + s0
//   E = Wu^T M Wi, a = Wu^T M bi, g = bu^T M Wi, s0 = bu^T M bi
// p_u = softmax_n(max_m S), p_i = softmax_m(max_n S)
//
// Round 8: one 1024-thread block per batch (16 waves = 4/SIMD, double R5's
// latency hiding at identical total work). Col-max via LDS ds_max_u32
// atomics on 4 shared slices (order-preserving uint encode) -> LDS 138 KB.
// Merged single prep kernel (P = Wu^T M row-factoring). Parallel softmaxes
// (waves 0-7 p_u, 8-15 p_i). MFMA chains split 3+3. Same verified tau
// fragment scheme as R5/R7.
// ws float layout: [4096..4159]=a, [4160..4223]=g, [4224]=s0,
//   ushort frags at ws+4352: EhiT[4096], EloT[4096]

#define NBATCH 256
#define NSEQ   512
#define DIM    64

typedef __attribute__((ext_vector_type(8))) short short8;
typedef __attribute__((ext_vector_type(4))) float f32x4;

#define MFMA16(a,b,c) __builtin_amdgcn_mfma_f32_16x16x32_bf16(a,b,c,0,0,0)

union BF2 { __hip_bfloat162 b; short2 s; };

__device__ __forceinline__ unsigned fenc(float x) {
    unsigned u = __float_as_uint(x);
    return (u >> 31) ? ~u : (u | 0x80000000u);
}
__device__ __forceinline__ float fdec(unsigned m) {
    unsigned u = (m >> 31) ? (m & 0x7FFFFFFFu) : ~m;
    return __uint_as_float(u);
}

__device__ __forceinline__ void cvt2(float f, unsigned short &h, unsigned short &l) {
    unsigned u = __float_as_uint(f);
    unsigned hb = (u + 0x7FFFu + ((u >> 16) & 1u)) >> 16;
    h = (unsigned short)hb;
    float r = f - __uint_as_float(hb << 16);
    unsigned u2 = __float_as_uint(r);
    l = (unsigned short)((u2 + 0x7FFFu + ((u2 >> 16) & 1u)) >> 16);
}

__device__ __forceinline__ void cvt8(const f32x4 a, const f32x4 b, short8 &hi, short8 &lo) {
    BF2 h0, h1, h2, h3;
    h0.b = __float22bfloat162_rn(make_float2(a[0], a[1]));
    h1.b = __float22bfloat162_rn(make_float2(a[2], a[3]));
    h2.b = __float22bfloat162_rn(make_float2(b[0], b[1]));
    h3.b = __float22bfloat162_rn(make_float2(b[2], b[3]));
    hi = short8{h0.s.x, h0.s.y, h1.s.x, h1.s.y, h2.s.x, h2.s.y, h3.s.x, h3.s.y};
    BF2 l0, l1, l2, l3;
    l0.b = __float22bfloat162_rn(make_float2(a[0] - __bfloat162float(h0.b.x),
                                             a[1] - __bfloat162float(h0.b.y)));
    l1.b = __float22bfloat162_rn(make_float2(a[2] - __bfloat162float(h1.b.x),
                                             a[3] - __bfloat162float(h1.b.y)));
    l2.b = __float22bfloat162_rn(make_float2(b[0] - __bfloat162float(h2.b.x),
                                             b[1] - __bfloat162float(h2.b.y)));
    l3.b = __float22bfloat162_rn(make_float2(b[2] - __bfloat162float(h3.b.x),
                                             b[3] - __bfloat162float(h3.b.y)));
    lo = short8{l0.s.x, l0.s.y, l1.s.x, l1.s.y, l2.s.x, l2.s.y, l3.s.x, l3.s.y};
}

// ---- merged prep: block c computes E[c,:] via P = Wu^T M (row c only),
//      frag-packs hi/lo, computes a[c]; block 0 also g[:] and s0 ----
__global__ __launch_bounds__(64) void coatt_prep(
    const float* __restrict__ M, const float* __restrict__ Wu,
    const float* __restrict__ bu, const float* __restrict__ Wi,
    const float* __restrict__ bi, float* __restrict__ ws)
{
    __shared__ float Wucol[64];
    __shared__ float Pc[64];
    __shared__ float qv[64];
    const int c = blockIdx.x, f = threadIdx.x;
    Wucol[f] = Wu[f*64 + c];
    __syncthreads();
    float p = 0.f;
    #pragma unroll 8
    for (int d = 0; d < 64; ++d) p = fmaf(Wucol[d], M[d*64 + f], p);
    Pc[f] = p;
    __syncthreads();
    float e = 0.f;
    #pragma unroll 8
    for (int k = 0; k < 64; ++k) e = fmaf(Pc[k], Wi[k*64 + f], e);
    // frag-pack E[k=c][f] (B-operand layout, same as prior rounds)
    unsigned short* efh = (unsigned short*)(ws + 4352);
    unsigned short* efl = efh + 4096;
    unsigned short h, l;
    cvt2(e, h, l);
    const int ko = c >> 5, quadc = (c >> 3) & 3, j = c & 7;
    const int ft = f >> 4, f15 = f & 15;
    const int pidx = ft*1024 + ko*512 + (quadc*16 + f15)*8 + j;
    efh[pidx] = h; efl[pidx] = l;
    // a[c] = P[c,:]·bi
    float pa = Pc[f] * bi[f];
    #pragma unroll
    for (int off = 1; off < 64; off <<= 1) pa += __shfl_xor(pa, off, 64);
    if (f == 0) ws[4096 + c] = pa;
    if (c == 0) {
        float q0 = 0.f;
        #pragma unroll 8
        for (int d = 0; d < 64; ++d) q0 = fmaf(bu[d], M[d*64 + f], q0);
        qv[f] = q0;
        __syncthreads();
        float gg = 0.f;
        #pragma unroll 8
        for (int k = 0; k < 64; ++k) gg = fmaf(qv[k], Wi[k*64 + f], gg);
        ws[4160 + f] = gg;
        float ps = qv[f] * bi[f];
        #pragma unroll
        for (int off = 1; off < 64; off <<= 1) ps += __shfl_xor(ps, off, 64);
        if (f == 0) ws[4224] = ps;
    }
}

// LDS (dynamic, bytes):
//  [0,65536)        YH  tau frag-packed bf16-hi of i_fea[b]
//  [65536,131072)   YL  bf16-lo
//  [131072,139264)  colp unsigned[2048]: 4 slices x 512 cols (ds_max_u32)
//  [139264,141312)  uscore float[512]
//  [141312,141440)  red float[32]
#define LDS_BYTES 141440

__global__ __launch_bounds__(1024, 1) void coatt_main(
    const float* __restrict__ u_fea, const float* __restrict__ i_fea,
    const float* __restrict__ ws, float* __restrict__ out)
{
    extern __shared__ char sm[];
    unsigned short* YH = (unsigned short*)sm;
    unsigned short* YL = (unsigned short*)(sm + 65536);
    unsigned* colp = (unsigned*)(sm + 131072);
    float* uscore  = (float*)(sm + 139264);
    float* red     = (float*)(sm + 141312);

    const int t    = threadIdx.x;
    const int lane = t & 63, w = t >> 6, quad = lane >> 4, l15 = lane & 15;
    const int b = blockIdx.x;
    const float* ub = u_fea + (size_t)b * NSEQ * DIM;
    const float* ib = i_fea + (size_t)b * NSEQ * DIM;

    // ---- Y global loads first (wave w packs tiles w*2, w*2+1) ----
    f32x4 ya[4], yb[4];
    #pragma unroll
    for (int q = 0; q < 4; ++q) {
        const int tile = w*2 + (q >> 1), p = q & 1;
        const float* yp = ib + (size_t)(tile*16 + l15)*DIM + p*16 + quad*4;
        ya[q] = *(const f32x4*)yp;
        yb[q] = *(const f32x4*)(yp + 32);
    }
    // ---- U global loads (wave w owns 32 n-rows) ----
    const int nbase = w*32;
    f32x4 u[2][4];
    #pragma unroll
    for (int g = 0; g < 2; ++g) {
        const float* up = ub + (size_t)(nbase + g*16 + l15)*DIM + quad*8;
        u[g][0] = *(const f32x4*)up;
        u[g][1] = *(const f32x4*)(up + 4);
        u[g][2] = *(const f32x4*)(up + 32);
        u[g][3] = *(const f32x4*)(up + 36);
    }
    // ---- colp init (encoded floor = 0) ----
    colp[t] = 0u;
    colp[1024 + t] = 0u;
    // ---- Y cvt + frag-packed LDS store (tau layout) ----
    #pragma unroll
    for (int q = 0; q < 4; ++q) {
        const int tile = w*2 + (q >> 1), p = q & 1;
        short8 sh, sl;
        cvt8(ya[q], yb[q], sh, sl);
        const int off = tile*1024 + p*512 + lane*8;
        *(short8*)(YH + off) = sh;
        *(short8*)(YL + off) = sl;
    }
    // ---- r[n] + U frags ----
    const f32x4 av0 = *(const f32x4*)(ws + 4096 + quad*8);
    const f32x4 av1 = *(const f32x4*)(ws + 4096 + quad*8 + 4);
    const f32x4 av2 = *(const f32x4*)(ws + 4096 + 32 + quad*8);
    const f32x4 av3 = *(const f32x4*)(ws + 4096 + 32 + quad*8 + 4);
    const float s0 = ws[4224];
    short8 UH[2][2], UL[2][2];
    f32x4 rv[2];
    #pragma unroll
    for (int g = 0; g < 2; ++g) {
        float rp = 0.f;
        #pragma unroll
        for (int e = 0; e < 4; ++e) rp = fmaf(u[g][0][e], av0[e], rp);
        #pragma unroll
        for (int e = 0; e < 4; ++e) rp = fmaf(u[g][1][e], av1[e], rp);
        #pragma unroll
        for (int e = 0; e < 4; ++e) rp = fmaf(u[g][2][e], av2[e], rp);
        #pragma unroll
        for (int e = 0; e < 4; ++e) rp = fmaf(u[g][3][e], av3[e], rp);
        rp += __shfl_xor(rp, 16, 64);
        rp += __shfl_xor(rp, 32, 64);
        rp += s0;
        cvt8(u[g][0], u[g][1], UH[g][0], UL[g][0]);
        cvt8(u[g][2], u[g][3], UH[g][1], UL[g][1]);
        #pragma unroll
        for (int rg = 0; rg < 4; ++rg)
            rv[g][rg] = __shfl(rp, quad*4 + rg, 64);
    }
    // ---- X-gen (transpose-free operand-swap; ft-pairs {p, p+2}) ----
    const unsigned short* efh = (const unsigned short*)(ws + 4352);
    const unsigned short* efl = efh + 4096;
    short8 XH[2][2], XL[2][2];
    #pragma unroll
    for (int p = 0; p < 2; ++p) {
        f32x4 ct[2][2];
        #pragma unroll
        for (int fh = 0; fh < 2; ++fh) {
            const int ft = p + fh*2;
            const short8 Eh0 = *(const short8*)(efh + (ft*2+0)*512 + lane*8);
            const short8 Eh1 = *(const short8*)(efh + (ft*2+1)*512 + lane*8);
            const short8 El0 = *(const short8*)(efl + (ft*2+0)*512 + lane*8);
            const short8 El1 = *(const short8*)(efl + (ft*2+1)*512 + lane*8);
            const f32x4 gq = *(const f32x4*)(ws + 4160 + ft*16 + quad*4);
            #pragma unroll
            for (int g = 0; g < 2; ++g) {
                f32x4 cA = gq;
                cA = MFMA16(Eh0, UH[g][0], cA);
                cA = MFMA16(Eh1, UH[g][1], cA);
                cA = MFMA16(Eh0, UL[g][0], cA);
                f32x4 cB = {0.f, 0.f, 0.f, 0.f};
                cB = MFMA16(Eh1, UL[g][1], cB);
                cB = MFMA16(El0, UH[g][0], cB);
                cB = MFMA16(El1, UH[g][1], cB);
                ct[g][fh] = cA + cB;
            }
        }
        #pragma unroll
        for (int g = 0; g < 2; ++g)
            cvt8(ct[g][0], ct[g][1], XH[g][p], XL[g][p]);
    }
    __syncthreads();   // Y + colp init visible

    // ---- S-loop over all 32 m-tiles ----
    f32x4 rm[2];
    rm[0] = (f32x4){-FLT_MAX, -FLT_MAX, -FLT_MAX, -FLT_MAX};
    rm[1] = rm[0];
    const int slice = (w & 3) * 512;
    for (int T = 0; T < 32; ++T) {
        const unsigned short* yh2 = YH + T*1024 + lane*8;
        const unsigned short* yl2 = YL + T*1024 + lane*8;
        const short8 BH0 = *(const short8*)(yh2);
        const short8 BH1 = *(const short8*)(yh2 + 512);
        const short8 BL0 = *(const short8*)(yl2);
        const short8 BL1 = *(const short8*)(yl2 + 512);
        float cg[2];
        #pragma unroll
        for (int g = 0; g < 2; ++g) {
            f32x4 cA = rv[g];              // +r[n] folded into C-init
            cA = MFMA16(XH[g][0], BH0, cA);
            cA = MFMA16(XH[g][1], BH1, cA);
            cA = MFMA16(XH[g][0], BL0, cA);
            f32x4 cB = {0.f, 0.f, 0.f, 0.f};
            cB = MFMA16(XH[g][1], BL1, cB);
            cB = MFMA16(XL[g][0], BH0, cB);
            cB = MFMA16(XL[g][1], BH1, cB);
            const f32x4 c = cA + cB;
            rm[g][0] = fmaxf(rm[g][0], c[0]);
            rm[g][1] = fmaxf(rm[g][1], c[1]);
            rm[g][2] = fmaxf(rm[g][2], c[2]);
            rm[g][3] = fmaxf(rm[g][3], c[3]);
            cg[g] = fmaxf(fmaxf(c[0], c[1]), fmaxf(c[2], c[3]));
        }
        float cm = fmaxf(cg[0], cg[1]);
        cm = fmaxf(cm, __shfl_xor(cm, 16, 64));
        cm = fmaxf(cm, __shfl_xor(cm, 32, 64));
        if (lane < 16) atomicMax(&colp[slice + T*16 + lane], fenc(cm));
    }
    // ---- row-max -> uscore ----
    #pragma unroll
    for (int g = 0; g < 2; ++g)
        #pragma unroll
        for (int rg = 0; rg < 4; ++rg) {
            float v = rm[g][rg];
            v = fmaxf(v, __shfl_xor(v, 1, 64));
            v = fmaxf(v, __shfl_xor(v, 2, 64));
            v = fmaxf(v, __shfl_xor(v, 4, 64));
            v = fmaxf(v, __shfl_xor(v, 8, 64));
            if (l15 == 0) uscore[nbase + g*16 + quad*4 + rg] = v;
        }
    __syncthreads();

    // ---- parallel softmaxes: waves 0-7 p_u, waves 8-15 p_i ----
    const int group = w >> 3, wg = w & 7, tg = t & 511;
    float v;
    if (group == 0) {
        v = uscore[tg];
    } else {
        v = fdec(colp[tg]);
        v = fmaxf(v, fdec(colp[512 + tg]));
        v = fmaxf(v, fdec(colp[1024 + tg]));
        v = fmaxf(v, fdec(colp[1536 + tg]));
    }
    float m = v;
    #pragma unroll
    for (int off = 1; off < 64; off <<= 1) m = fmaxf(m, __shfl_xor(m, off, 64));
    if (lane == 0) red[group*8 + wg] = m;
    __syncthreads();
    m = red[group*8];
    #pragma unroll
    for (int q = 1; q < 8; ++q) m = fmaxf(m, red[group*8 + q]);
    const float e = __expf(v - m);
    float s = e;
    #pragma unroll
    for (int off = 1; off < 64; off <<= 1) s += __shfl_xor(s, off, 64);
    if (lane == 0) red[16 + group*8 + wg] = s;
    __syncthreads();
    float sum = red[16 + group*8];
    #pragma unroll
    for (int q = 1; q < 8; ++q) sum += red[16 + group*8 + q];
    const size_t obase = group ? ((size_t)NBATCH*NSEQ + (size_t)b*NSEQ)
                               : ((size_t)b*NSEQ);
    out[obase + tg] = e * (1.0f / sum);
}

extern "C" void kernel_launch(void* const* d_in, const int* in_sizes, int n_in,
                              void* d_out, int out_size, void* d_ws, size_t ws_size,
                              hipStream_t stream) {
    const float* u_fea = (const float*)d_in[0];
    const float* i_fea = (const float*)d_in[1];
    const float* M     = (const float*)d_in[2];
    const float* Wu    = (const float*)d_in[3];
    const float* bu    = (const float*)d_in[4];
    const float* Wi    = (const float*)d_in[5];
    const float* bi    = (const float*)d_in[6];
    float* out = (float*)d_out;
    float* ws  = (float*)d_ws;

    coatt_prep<<<64, 64, 0, stream>>>(M, Wu, bu, Wi, bi, ws);
    coatt_main<<<NBATCH, 1024, LDS_BYTES, stream>>>(u_fea, i_fea, ws, out);
}

// Round 9
// 197.578 us; speedup vs baseline: 1.2110x; 1.2110x over previous
//
#include <hip/hip_runtime.h>
#include <hip/hip_bf16.h>
#include <float.h>

// Co_Attention collapsed:
//   S[b,n,m] = u_fea[b,n]·E·i_fea[b,m] + u_fea[b,n]·a + g·i_fea[b,m] + s0
//   E = Wu^T M Wi, a = Wu^T M bi, g = bu^T M Wi, s0 = bu^T M bi
// p_u = softmax_n(max_m S), p_i = softmax_m(max_n S)
//
// Round 9: R5 work-shape (1 block/batch, 512 thr, 8 waves, full X in regs,
// all 32 m-tiles) but Y staged in TWO 256-row phases -> LDS 74 KB -> two
// different-batch blocks co-reside per CU = 4 waves/SIMD with no duplicated
// work. Col-max via LDS atomicMax on order-preserving uint floats (R8-
// verified). 512-thr blocks + __launch_bounds__(512,2) = the proven no-spill
// config (1024-thr or (512,4) force a 64-VGPR cap and catastrophic spills).
// ws float layout: [4096..4159]=a, [4160..4223]=g, [4224]=s0,
//   ushort frags at ws+4352: EhiT[4096], EloT[4096]

#define NBATCH 256
#define NSEQ   512
#define DIM    64

typedef __attribute__((ext_vector_type(8))) short short8;
typedef __attribute__((ext_vector_type(4))) float f32x4;

#define MFMA16(a,b,c) __builtin_amdgcn_mfma_f32_16x16x32_bf16(a,b,c,0,0,0)

union BF2 { __hip_bfloat162 b; short2 s; };

__device__ __forceinline__ unsigned fenc(float x) {
    unsigned u = __float_as_uint(x);
    return (u >> 31) ? ~u : (u | 0x80000000u);
}
__device__ __forceinline__ float fdec(unsigned m) {
    unsigned u = (m >> 31) ? (m & 0x7FFFFFFFu) : ~m;
    return __uint_as_float(u);
}

__device__ __forceinline__ void cvt2(float f, unsigned short &h, unsigned short &l) {
    unsigned u = __float_as_uint(f);
    unsigned hb = (u + 0x7FFFu + ((u >> 16) & 1u)) >> 16;
    h = (unsigned short)hb;
    float r = f - __uint_as_float(hb << 16);
    unsigned u2 = __float_as_uint(r);
    l = (unsigned short)((u2 + 0x7FFFu + ((u2 >> 16) & 1u)) >> 16);
}

__device__ __forceinline__ void cvt8(const f32x4 a, const f32x4 b, short8 &hi, short8 &lo) {
    BF2 h0, h1, h2, h3;
    h0.b = __float22bfloat162_rn(make_float2(a[0], a[1]));
    h1.b = __float22bfloat162_rn(make_float2(a[2], a[3]));
    h2.b = __float22bfloat162_rn(make_float2(b[0], b[1]));
    h3.b = __float22bfloat162_rn(make_float2(b[2], b[3]));
    hi = short8{h0.s.x, h0.s.y, h1.s.x, h1.s.y, h2.s.x, h2.s.y, h3.s.x, h3.s.y};
    BF2 l0, l1, l2, l3;
    l0.b = __float22bfloat162_rn(make_float2(a[0] - __bfloat162float(h0.b.x),
                                             a[1] - __bfloat162float(h0.b.y)));
    l1.b = __float22bfloat162_rn(make_float2(a[2] - __bfloat162float(h1.b.x),
                                             a[3] - __bfloat162float(h1.b.y)));
    l2.b = __float22bfloat162_rn(make_float2(b[0] - __bfloat162float(h2.b.x),
                                             b[1] - __bfloat162float(h2.b.y)));
    l3.b = __float22bfloat162_rn(make_float2(b[2] - __bfloat162float(h3.b.x),
                                             b[3] - __bfloat162float(h3.b.y)));
    lo = short8{l0.s.x, l0.s.y, l1.s.x, l1.s.y, l2.s.x, l2.s.y, l3.s.x, l3.s.y};
}

// ---- merged prep (R8-verified): block c computes E[c,:] via P = Wu^T M,
//      frag-packs hi/lo, computes a[c]; block 0 also g[:] and s0 ----
__global__ __launch_bounds__(64) void coatt_prep(
    const float* __restrict__ M, const float* __restrict__ Wu,
    const float* __restrict__ bu, const float* __restrict__ Wi,
    const float* __restrict__ bi, float* __restrict__ ws)
{
    __shared__ float Wucol[64];
    __shared__ float Pc[64];
    __shared__ float qv[64];
    const int c = blockIdx.x, f = threadIdx.x;
    Wucol[f] = Wu[f*64 + c];
    __syncthreads();
    float p = 0.f;
    #pragma unroll 8
    for (int d = 0; d < 64; ++d) p = fmaf(Wucol[d], M[d*64 + f], p);
    Pc[f] = p;
    __syncthreads();
    float e = 0.f;
    #pragma unroll 8
    for (int k = 0; k < 64; ++k) e = fmaf(Pc[k], Wi[k*64 + f], e);
    unsigned short* efh = (unsigned short*)(ws + 4352);
    unsigned short* efl = efh + 4096;
    unsigned short h, l;
    cvt2(e, h, l);
    const int ko = c >> 5, quadc = (c >> 3) & 3, j = c & 7;
    const int ft = f >> 4, f15 = f & 15;
    const int pidx = ft*1024 + ko*512 + (quadc*16 + f15)*8 + j;
    efh[pidx] = h; efl[pidx] = l;
    float pa = Pc[f] * bi[f];
    #pragma unroll
    for (int off = 1; off < 64; off <<= 1) pa += __shfl_xor(pa, off, 64);
    if (f == 0) ws[4096 + c] = pa;
    if (c == 0) {
        float q0 = 0.f;
        #pragma unroll 8
        for (int d = 0; d < 64; ++d) q0 = fmaf(bu[d], M[d*64 + f], q0);
        qv[f] = q0;
        __syncthreads();
        float gg = 0.f;
        #pragma unroll 8
        for (int k = 0; k < 64; ++k) gg = fmaf(qv[k], Wi[k*64 + f], gg);
        ws[4160 + f] = gg;
        float ps = qv[f] * bi[f];
        #pragma unroll
        for (int off = 1; off < 64; off <<= 1) ps += __shfl_xor(ps, off, 64);
        if (f == 0) ws[4224] = ps;
    }
}

// LDS (dynamic, bytes):
//  [0,32768)        YH  tau frag-packed bf16-hi of current 256-row Y phase
//  [32768,65536)    YL  bf16-lo
//  [65536,73728)    colp unsigned[2048]: 4 slices x 512 cols (ds atomicMax)
//  [73728,75776)    uscore float[512]
//  [75776,75840)    red float[16]
#define LDS_BYTES 75840

__global__ __launch_bounds__(512, 2) void coatt_main(
    const float* __restrict__ u_fea, const float* __restrict__ i_fea,
    const float* __restrict__ ws, float* __restrict__ out)
{
    extern __shared__ char sm[];
    unsigned short* YH = (unsigned short*)sm;
    unsigned short* YL = (unsigned short*)(sm + 32768);
    unsigned* colp = (unsigned*)(sm + 65536);
    float* uscore  = (float*)(sm + 73728);
    float* red     = (float*)(sm + 75776);

    const int t    = threadIdx.x;
    const int lane = t & 63, w = t >> 6, quad = lane >> 4, l15 = lane & 15;
    const int b = blockIdx.x;
    const float* ub = u_fea + (size_t)b * NSEQ * DIM;
    const float* ib = i_fea + (size_t)b * NSEQ * DIM;

    // ---- colp init (encoded floor) ----
    #pragma unroll
    for (int i = 0; i < 4; ++i) colp[i*512 + t] = 0u;

    // ---- E fragments (regs; B-operand pack used as A-operand, R5 scheme) ----
    const unsigned short* efh = (const unsigned short*)(ws + 4352);
    const unsigned short* efl = efh + 4096;
    short8 EH[4][2], EL[4][2];
    #pragma unroll
    for (int ft = 0; ft < 4; ++ft)
        #pragma unroll
        for (int ko = 0; ko < 2; ++ko) {
            EH[ft][ko] = *(const short8*)(efh + ((ft*2+ko)*64 + lane)*8);
            EL[ft][ko] = *(const short8*)(efl + ((ft*2+ko)*64 + lane)*8);
        }
    f32x4 gq[4];
    #pragma unroll
    for (int ft = 0; ft < 4; ++ft) gq[ft] = *(const f32x4*)(ws + 4160 + ft*16 + quad*4);
    const f32x4 av0 = *(const f32x4*)(ws + 4096 + quad*8);
    const f32x4 av1 = *(const f32x4*)(ws + 4096 + quad*8 + 4);
    const f32x4 av2 = *(const f32x4*)(ws + 4096 + 32 + quad*8);
    const f32x4 av3 = *(const f32x4*)(ws + 4096 + 32 + quad*8 + 4);
    const float s0 = ws[4224];

    // ---- phase-0 Y pack (rows 0..255; wave w packs local tiles w*2,w*2+1) ----
    #pragma unroll
    for (int q = 0; q < 4; ++q) {
        const int tl = w*2 + (q >> 1), p = q & 1;
        const float* yp = ib + (size_t)(tl*16 + l15)*DIM + p*16 + quad*4;
        const f32x4 a0 = *(const f32x4*)yp;
        const f32x4 b0 = *(const f32x4*)(yp + 32);
        short8 sh, sl;
        cvt8(a0, b0, sh, sl);
        const int off = tl*1024 + p*512 + lane*8;
        *(short8*)(YH + off) = sh;
        *(short8*)(YL + off) = sl;
    }

    // ---- X-gen: wave w owns 64 n-rows; X^T = E^T U^T operand-swap; frags in regs ----
    const int base = w*64;
    short8 XH[4][2], XL[4][2];
    f32x4 rv[4];
    #pragma unroll
    for (int g = 0; g < 4; ++g) {
        const float* up = ub + (size_t)(base + g*16 + l15)*DIM + quad*8;
        const f32x4 u0 = *(const f32x4*)up;
        const f32x4 u1 = *(const f32x4*)(up + 4);
        const f32x4 u2 = *(const f32x4*)(up + 32);
        const f32x4 u3 = *(const f32x4*)(up + 36);
        float rp = 0.f;
        #pragma unroll
        for (int e = 0; e < 4; ++e) rp = fmaf(u0[e], av0[e], rp);
        #pragma unroll
        for (int e = 0; e < 4; ++e) rp = fmaf(u1[e], av1[e], rp);
        #pragma unroll
        for (int e = 0; e < 4; ++e) rp = fmaf(u2[e], av2[e], rp);
        #pragma unroll
        for (int e = 0; e < 4; ++e) rp = fmaf(u3[e], av3[e], rp);
        rp += __shfl_xor(rp, 16, 64);
        rp += __shfl_xor(rp, 32, 64);
        rp += s0;
        short8 UH0, UL0, UH1, UL1;
        cvt8(u0, u1, UH0, UL0);
        cvt8(u2, u3, UH1, UL1);
        f32x4 ct[4];
        #pragma unroll
        for (int ft = 0; ft < 4; ++ft) {
            f32x4 cA = gq[ft];
            cA = MFMA16(EH[ft][0], UH0, cA);
            cA = MFMA16(EH[ft][1], UH1, cA);
            cA = MFMA16(EH[ft][0], UL0, cA);
            f32x4 cB = {0.f, 0.f, 0.f, 0.f};
            cB = MFMA16(EH[ft][1], UL1, cB);
            cB = MFMA16(EL[ft][0], UH0, cB);
            cB = MFMA16(EL[ft][1], UH1, cB);
            ct[ft] = cA + cB;
        }
        cvt8(ct[0], ct[2], XH[g][0], XL[g][0]);
        cvt8(ct[1], ct[3], XH[g][1], XL[g][1]);
        #pragma unroll
        for (int rg = 0; rg < 4; ++rg)
            rv[g][rg] = __shfl(rp, quad*4 + rg, 64);
    }

    // ---- two-phase S-loop ----
    f32x4 rm[4];
    #pragma unroll
    for (int g = 0; g < 4; ++g)
        rm[g] = (f32x4){-FLT_MAX, -FLT_MAX, -FLT_MAX, -FLT_MAX};
    const int slice = (w & 3) * 512;

    #pragma unroll
    for (int h = 0; h < 2; ++h) {
        if (h == 1) {
            __syncthreads();   // phase-0 reads done before overwrite
            #pragma unroll
            for (int q = 0; q < 4; ++q) {
                const int tl = w*2 + (q >> 1), p = q & 1;
                const float* yp = ib + (size_t)(256 + tl*16 + l15)*DIM + p*16 + quad*4;
                const f32x4 a0 = *(const f32x4*)yp;
                const f32x4 b0 = *(const f32x4*)(yp + 32);
                short8 sh, sl;
                cvt8(a0, b0, sh, sl);
                const int off = tl*1024 + p*512 + lane*8;
                *(short8*)(YH + off) = sh;
                *(short8*)(YL + off) = sl;
            }
        }
        __syncthreads();   // Y (and colp init at h=0) visible

        for (int T = 0; T < 16; ++T) {
            const unsigned short* yh2 = YH + T*1024 + lane*8;
            const unsigned short* yl2 = YL + T*1024 + lane*8;
            const short8 BH0 = *(const short8*)(yh2);
            const short8 BH1 = *(const short8*)(yh2 + 512);
            const short8 BL0 = *(const short8*)(yl2);
            const short8 BL1 = *(const short8*)(yl2 + 512);
            float cg[4];
            #pragma unroll
            for (int g = 0; g < 4; ++g) {
                f32x4 cA = rv[g];              // +r[n] folded into C-init
                cA = MFMA16(XH[g][0], BH0, cA);
                cA = MFMA16(XH[g][1], BH1, cA);
                cA = MFMA16(XH[g][0], BL0, cA);
                f32x4 cB = {0.f, 0.f, 0.f, 0.f};
                cB = MFMA16(XH[g][1], BL1, cB);
                cB = MFMA16(XL[g][0], BH0, cB);
                cB = MFMA16(XL[g][1], BH1, cB);
                const f32x4 c = cA + cB;
                rm[g][0] = fmaxf(rm[g][0], c[0]);
                rm[g][1] = fmaxf(rm[g][1], c[1]);
                rm[g][2] = fmaxf(rm[g][2], c[2]);
                rm[g][3] = fmaxf(rm[g][3], c[3]);
                cg[g] = fmaxf(fmaxf(c[0], c[1]), fmaxf(c[2], c[3]));
            }
            float cm = fmaxf(fmaxf(cg[0], cg[1]), fmaxf(cg[2], cg[3]));
            cm = fmaxf(cm, __shfl_xor(cm, 16, 64));
            cm = fmaxf(cm, __shfl_xor(cm, 32, 64));
            if (lane < 16)
                atomicMax(&colp[slice + h*256 + T*16 + lane], fenc(cm));
        }
    }

    // ---- row-max -> uscore ----
    #pragma unroll
    for (int g = 0; g < 4; ++g)
        #pragma unroll
        for (int rg = 0; rg < 4; ++rg) {
            float v = rm[g][rg];
            v = fmaxf(v, __shfl_xor(v, 1, 64));
            v = fmaxf(v, __shfl_xor(v, 2, 64));
            v = fmaxf(v, __shfl_xor(v, 4, 64));
            v = fmaxf(v, __shfl_xor(v, 8, 64));
            if (l15 == 0) uscore[base + g*16 + quad*4 + rg] = v;
        }
    __syncthreads();

    // ---- softmax(uscore) -> p_u ----
    {
        const float v = uscore[t];
        float m = v;
        #pragma unroll
        for (int off = 1; off < 64; off <<= 1) m = fmaxf(m, __shfl_xor(m, off, 64));
        if (lane == 0) red[w] = m;
        __syncthreads();
        m = red[0];
        #pragma unroll
        for (int q = 1; q < 8; ++q) m = fmaxf(m, red[q]);
        const float e = __expf(v - m);
        float s = e;
        #pragma unroll
        for (int off = 1; off < 64; off <<= 1) s += __shfl_xor(s, off, 64);
        if (lane == 0) red[8+w] = s;
        __syncthreads();
        float sum = red[8];
        #pragma unroll
        for (int q = 1; q < 8; ++q) sum += red[8+q];
        out[(size_t)b*NSEQ + t] = e * (1.0f / sum);
    }
    __syncthreads();
    // ---- softmax(col max over 4 slices) -> p_i ----
    {
        float v = fdec(colp[t]);
        v = fmaxf(v, fdec(colp[512 + t]));
        v = fmaxf(v, fdec(colp[1024 + t]));
        v = fmaxf(v, fdec(colp[1536 + t]));
        float m = v;
        #pragma unroll
        for (int off = 1; off < 64; off <<= 1) m = fmaxf(m, __shfl_xor(m, off, 64));
        if (lane == 0) red[w] = m;
        __syncthreads();
        m = red[0];
        #pragma unroll
        for (int q = 1; q < 8; ++q) m = fmaxf(m, red[q]);
        const float e = __expf(v - m);
        float s = e;
        #pragma unroll
        for (int off = 1; off < 64; off <<= 1) s += __shfl_xor(s, off, 64);
        if (lane == 0) red[8+w] = s;
        __syncthreads();
        float sum = red[8];
        #pragma unroll
        for (int q = 1; q < 8; ++q) sum += red[8+q];
        out[(size_t)NBATCH*NSEQ + (size_t)b*NSEQ + t] = e * (1.0f / sum);
    }
}

extern "C" void kernel_launch(void* const* d_in, const int* in_sizes, int n_in,
                              void* d_out, int out_size, void* d_ws, size_t ws_size,
                              hipStream_t stream) {
    const float* u_fea = (const float*)d_in[0];
    const float* i_fea = (const float*)d_in[1];
    const float* M     = (const float*)d_in[2];
    const float* Wu    = (const float*)d_in[3];
    const float* bu    = (const float*)d_in[4];
    const float* Wi    = (const float*)d_in[5];
    const float* bi    = (const float*)d_in[6];
    float* out = (float*)d_out;
    float* ws  = (float*)d_ws;

    coatt_prep<<<64, 64, 0, stream>>>(M, Wu, bu, Wi, bi, ws);
    coatt_main<<<NBATCH, 512, LDS_BYTES, stream>>>(u_fea, i_fea, ws, out);
}

// Round 10
// 135.936 us; speedup vs baseline: 1.7602x; 1.4535x over previous
//
#include <hip/hip_runtime.h>
#include <hip/hip_bf16.h>
#include <float.h>

// Co_Attention collapsed:
//   S[b,n,m] = u_fea[b,n]·E·i_fea[b,m] + u_fea[b,n]·a + g·i_fea[b,m] + s0
//   E = Wu^T M Wi, a = Wu^T M bi, g = bu^T M Wi, s0 = bu^T M bi
// p_u = softmax_n(max_m S), p_i = softmax_m(max_n S)
//
// Round 10: R9 two-phase structure (74 KB LDS -> 2 blocks/CU = 4 waves/SIMD,
// no duplicated work) with the spill fixed: phase-1 Y-repack is #pragma
// unroll 1 (one q's load/cvt temps live at a time; R9's unrolled version
// needed >128 VGPR and spilled 166 MB of scratch). S-loop unroll capped at 2.
// 512-thr + __launch_bounds__(512,2) = proven no-spill envelope when demand
// stays under 128.
// ws float layout: [4096..4159]=a, [4160..4223]=g, [4224]=s0,
//   ushort frags at ws+4352: EhiT[4096], EloT[4096]

#define NBATCH 256
#define NSEQ   512
#define DIM    64

typedef __attribute__((ext_vector_type(8))) short short8;
typedef __attribute__((ext_vector_type(4))) float f32x4;

#define MFMA16(a,b,c) __builtin_amdgcn_mfma_f32_16x16x32_bf16(a,b,c,0,0,0)

union BF2 { __hip_bfloat162 b; short2 s; };

__device__ __forceinline__ unsigned fenc(float x) {
    unsigned u = __float_as_uint(x);
    return (u >> 31) ? ~u : (u | 0x80000000u);
}
__device__ __forceinline__ float fdec(unsigned m) {
    unsigned u = (m >> 31) ? (m & 0x7FFFFFFFu) : ~m;
    return __uint_as_float(u);
}

__device__ __forceinline__ void cvt2(float f, unsigned short &h, unsigned short &l) {
    unsigned u = __float_as_uint(f);
    unsigned hb = (u + 0x7FFFu + ((u >> 16) & 1u)) >> 16;
    h = (unsigned short)hb;
    float r = f - __uint_as_float(hb << 16);
    unsigned u2 = __float_as_uint(r);
    l = (unsigned short)((u2 + 0x7FFFu + ((u2 >> 16) & 1u)) >> 16);
}

__device__ __forceinline__ void cvt8(const f32x4 a, const f32x4 b, short8 &hi, short8 &lo) {
    BF2 h0, h1, h2, h3;
    h0.b = __float22bfloat162_rn(make_float2(a[0], a[1]));
    h1.b = __float22bfloat162_rn(make_float2(a[2], a[3]));
    h2.b = __float22bfloat162_rn(make_float2(b[0], b[1]));
    h3.b = __float22bfloat162_rn(make_float2(b[2], b[3]));
    hi = short8{h0.s.x, h0.s.y, h1.s.x, h1.s.y, h2.s.x, h2.s.y, h3.s.x, h3.s.y};
    BF2 l0, l1, l2, l3;
    l0.b = __float22bfloat162_rn(make_float2(a[0] - __bfloat162float(h0.b.x),
                                             a[1] - __bfloat162float(h0.b.y)));
    l1.b = __float22bfloat162_rn(make_float2(a[2] - __bfloat162float(h1.b.x),
                                             a[3] - __bfloat162float(h1.b.y)));
    l2.b = __float22bfloat162_rn(make_float2(b[0] - __bfloat162float(h2.b.x),
                                             b[1] - __bfloat162float(h2.b.y)));
    l3.b = __float22bfloat162_rn(make_float2(b[2] - __bfloat162float(h3.b.x),
                                             b[3] - __bfloat162float(h3.b.y)));
    lo = short8{l0.s.x, l0.s.y, l1.s.x, l1.s.y, l2.s.x, l2.s.y, l3.s.x, l3.s.y};
}

// ---- merged prep (verified): block c computes E[c,:] via P = Wu^T M,
//      frag-packs hi/lo, computes a[c]; block 0 also g[:] and s0 ----
__global__ __launch_bounds__(64) void coatt_prep(
    const float* __restrict__ M, const float* __restrict__ Wu,
    const float* __restrict__ bu, const float* __restrict__ Wi,
    const float* __restrict__ bi, float* __restrict__ ws)
{
    __shared__ float Wucol[64];
    __shared__ float Pc[64];
    __shared__ float qv[64];
    const int c = blockIdx.x, f = threadIdx.x;
    Wucol[f] = Wu[f*64 + c];
    __syncthreads();
    float p = 0.f;
    #pragma unroll 8
    for (int d = 0; d < 64; ++d) p = fmaf(Wucol[d], M[d*64 + f], p);
    Pc[f] = p;
    __syncthreads();
    float e = 0.f;
    #pragma unroll 8
    for (int k = 0; k < 64; ++k) e = fmaf(Pc[k], Wi[k*64 + f], e);
    unsigned short* efh = (unsigned short*)(ws + 4352);
    unsigned short* efl = efh + 4096;
    unsigned short h, l;
    cvt2(e, h, l);
    const int ko = c >> 5, quadc = (c >> 3) & 3, j = c & 7;
    const int ft = f >> 4, f15 = f & 15;
    const int pidx = ft*1024 + ko*512 + (quadc*16 + f15)*8 + j;
    efh[pidx] = h; efl[pidx] = l;
    float pa = Pc[f] * bi[f];
    #pragma unroll
    for (int off = 1; off < 64; off <<= 1) pa += __shfl_xor(pa, off, 64);
    if (f == 0) ws[4096 + c] = pa;
    if (c == 0) {
        float q0 = 0.f;
        #pragma unroll 8
        for (int d = 0; d < 64; ++d) q0 = fmaf(bu[d], M[d*64 + f], q0);
        qv[f] = q0;
        __syncthreads();
        float gg = 0.f;
        #pragma unroll 8
        for (int k = 0; k < 64; ++k) gg = fmaf(qv[k], Wi[k*64 + f], gg);
        ws[4160 + f] = gg;
        float ps = qv[f] * bi[f];
        #pragma unroll
        for (int off = 1; off < 64; off <<= 1) ps += __shfl_xor(ps, off, 64);
        if (f == 0) ws[4224] = ps;
    }
}

// LDS (dynamic, bytes):
//  [0,32768)        YH  tau frag-packed bf16-hi of current 256-row Y phase
//  [32768,65536)    YL  bf16-lo
//  [65536,73728)    colp unsigned[2048]: 4 slices x 512 cols (ds atomicMax)
//  [73728,75776)    uscore float[512]
//  [75776,75840)    red float[16]
#define LDS_BYTES 75840

__global__ __launch_bounds__(512, 2) void coatt_main(
    const float* __restrict__ u_fea, const float* __restrict__ i_fea,
    const float* __restrict__ ws, float* __restrict__ out)
{
    extern __shared__ char sm[];
    unsigned short* YH = (unsigned short*)sm;
    unsigned short* YL = (unsigned short*)(sm + 32768);
    unsigned* colp = (unsigned*)(sm + 65536);
    float* uscore  = (float*)(sm + 73728);
    float* red     = (float*)(sm + 75776);

    const int t    = threadIdx.x;
    const int lane = t & 63, w = t >> 6, quad = lane >> 4, l15 = lane & 15;
    const int b = blockIdx.x;
    const float* ub = u_fea + (size_t)b * NSEQ * DIM;
    const float* ib = i_fea + (size_t)b * NSEQ * DIM;

    // ---- colp init (encoded floor) ----
    #pragma unroll
    for (int i = 0; i < 4; ++i) colp[i*512 + t] = 0u;

    // ---- E fragments (regs; B-operand pack used as A-operand) ----
    const unsigned short* efh = (const unsigned short*)(ws + 4352);
    const unsigned short* efl = efh + 4096;
    short8 EH[4][2], EL[4][2];
    #pragma unroll
    for (int ft = 0; ft < 4; ++ft)
        #pragma unroll
        for (int ko = 0; ko < 2; ++ko) {
            EH[ft][ko] = *(const short8*)(efh + ((ft*2+ko)*64 + lane)*8);
            EL[ft][ko] = *(const short8*)(efl + ((ft*2+ko)*64 + lane)*8);
        }
    f32x4 gq[4];
    #pragma unroll
    for (int ft = 0; ft < 4; ++ft) gq[ft] = *(const f32x4*)(ws + 4160 + ft*16 + quad*4);
    const f32x4 av0 = *(const f32x4*)(ws + 4096 + quad*8);
    const f32x4 av1 = *(const f32x4*)(ws + 4096 + quad*8 + 4);
    const f32x4 av2 = *(const f32x4*)(ws + 4096 + 32 + quad*8);
    const f32x4 av3 = *(const f32x4*)(ws + 4096 + 32 + quad*8 + 4);
    const float s0 = ws[4224];

    // ---- phase-0 Y pack (rows 0..255; wave w packs local tiles w*2,w*2+1) ----
    #pragma unroll
    for (int q = 0; q < 4; ++q) {
        const int tl = w*2 + (q >> 1), p = q & 1;
        const float* yp = ib + (size_t)(tl*16 + l15)*DIM + p*16 + quad*4;
        const f32x4 a0 = *(const f32x4*)yp;
        const f32x4 b0 = *(const f32x4*)(yp + 32);
        short8 sh, sl;
        cvt8(a0, b0, sh, sl);
        const int off = tl*1024 + p*512 + lane*8;
        *(short8*)(YH + off) = sh;
        *(short8*)(YL + off) = sl;
    }

    // ---- X-gen: wave w owns 64 n-rows; X^T = E^T U^T operand-swap ----
    const int base = w*64;
    short8 XH[4][2], XL[4][2];
    f32x4 rv[4];
    #pragma unroll
    for (int g = 0; g < 4; ++g) {
        const float* up = ub + (size_t)(base + g*16 + l15)*DIM + quad*8;
        const f32x4 u0 = *(const f32x4*)up;
        const f32x4 u1 = *(const f32x4*)(up + 4);
        const f32x4 u2 = *(const f32x4*)(up + 32);
        const f32x4 u3 = *(const f32x4*)(up + 36);
        float rp = 0.f;
        #pragma unroll
        for (int e = 0; e < 4; ++e) rp = fmaf(u0[e], av0[e], rp);
        #pragma unroll
        for (int e = 0; e < 4; ++e) rp = fmaf(u1[e], av1[e], rp);
        #pragma unroll
        for (int e = 0; e < 4; ++e) rp = fmaf(u2[e], av2[e], rp);
        #pragma unroll
        for (int e = 0; e < 4; ++e) rp = fmaf(u3[e], av3[e], rp);
        rp += __shfl_xor(rp, 16, 64);
        rp += __shfl_xor(rp, 32, 64);
        rp += s0;
        short8 UH0, UL0, UH1, UL1;
        cvt8(u0, u1, UH0, UL0);
        cvt8(u2, u3, UH1, UL1);
        f32x4 ct[4];
        #pragma unroll
        for (int ft = 0; ft < 4; ++ft) {
            f32x4 cA = gq[ft];
            cA = MFMA16(EH[ft][0], UH0, cA);
            cA = MFMA16(EH[ft][1], UH1, cA);
            cA = MFMA16(EH[ft][0], UL0, cA);
            f32x4 cB = {0.f, 0.f, 0.f, 0.f};
            cB = MFMA16(EH[ft][1], UL1, cB);
            cB = MFMA16(EL[ft][0], UH0, cB);
            cB = MFMA16(EL[ft][1], UH1, cB);
            ct[ft] = cA + cB;
        }
        cvt8(ct[0], ct[2], XH[g][0], XL[g][0]);
        cvt8(ct[1], ct[3], XH[g][1], XL[g][1]);
        #pragma unroll
        for (int rg = 0; rg < 4; ++rg)
            rv[g][rg] = __shfl(rp, quad*4 + rg, 64);
    }

    // ---- two-phase S-loop ----
    f32x4 rm[4];
    #pragma unroll
    for (int g = 0; g < 4; ++g)
        rm[g] = (f32x4){-FLT_MAX, -FLT_MAX, -FLT_MAX, -FLT_MAX};
    const int slice = (w & 3) * 512;

    #pragma unroll
    for (int h = 0; h < 2; ++h) {
        if (h == 1) {
            __syncthreads();   // phase-0 reads done before overwrite
            // unroll 1: one q's load/cvt temps live at a time (spill control)
            #pragma unroll 1
            for (int q = 0; q < 4; ++q) {
                const int tl = w*2 + (q >> 1), p = q & 1;
                const float* yp = ib + (size_t)(256 + tl*16 + l15)*DIM + p*16 + quad*4;
                const f32x4 a0 = *(const f32x4*)yp;
                const f32x4 b0 = *(const f32x4*)(yp + 32);
                short8 sh, sl;
                cvt8(a0, b0, sh, sl);
                const int off = tl*1024 + p*512 + lane*8;
                *(short8*)(YH + off) = sh;
                *(short8*)(YL + off) = sl;
            }
        }
        __syncthreads();   // Y (and colp init at h=0) visible

        #pragma unroll 2
        for (int T = 0; T < 16; ++T) {
            const unsigned short* yh2 = YH + T*1024 + lane*8;
            const unsigned short* yl2 = YL + T*1024 + lane*8;
            const short8 BH0 = *(const short8*)(yh2);
            const short8 BH1 = *(const short8*)(yh2 + 512);
            const short8 BL0 = *(const short8*)(yl2);
            const short8 BL1 = *(const short8*)(yl2 + 512);
            float cm = -FLT_MAX;
            #pragma unroll
            for (int g = 0; g < 4; ++g) {
                f32x4 cA = rv[g];              // +r[n] folded into C-init
                cA = MFMA16(XH[g][0], BH0, cA);
                cA = MFMA16(XH[g][1], BH1, cA);
                cA = MFMA16(XH[g][0], BL0, cA);
                f32x4 cB = {0.f, 0.f, 0.f, 0.f};
                cB = MFMA16(XH[g][1], BL1, cB);
                cB = MFMA16(XL[g][0], BH0, cB);
                cB = MFMA16(XL[g][1], BH1, cB);
                const f32x4 c = cA + cB;
                rm[g][0] = fmaxf(rm[g][0], c[0]);
                rm[g][1] = fmaxf(rm[g][1], c[1]);
                rm[g][2] = fmaxf(rm[g][2], c[2]);
                rm[g][3] = fmaxf(rm[g][3], c[3]);
                cm = fmaxf(cm, fmaxf(fmaxf(c[0], c[1]), fmaxf(c[2], c[3])));
            }
            cm = fmaxf(cm, __shfl_xor(cm, 16, 64));
            cm = fmaxf(cm, __shfl_xor(cm, 32, 64));
            if (lane < 16)
                atomicMax(&colp[slice + h*256 + T*16 + lane], fenc(cm));
        }
    }

    // ---- row-max -> uscore ----
    #pragma unroll
    for (int g = 0; g < 4; ++g)
        #pragma unroll
        for (int rg = 0; rg < 4; ++rg) {
            float v = rm[g][rg];
            v = fmaxf(v, __shfl_xor(v, 1, 64));
            v = fmaxf(v, __shfl_xor(v, 2, 64));
            v = fmaxf(v, __shfl_xor(v, 4, 64));
            v = fmaxf(v, __shfl_xor(v, 8, 64));
            if (l15 == 0) uscore[base + g*16 + quad*4 + rg] = v;
        }
    __syncthreads();

    // ---- softmax(uscore) -> p_u ----
    {
        const float v = uscore[t];
        float m = v;
        #pragma unroll
        for (int off = 1; off < 64; off <<= 1) m = fmaxf(m, __shfl_xor(m, off, 64));
        if (lane == 0) red[w] = m;
        __syncthreads();
        m = red[0];
        #pragma unroll
        for (int q = 1; q < 8; ++q) m = fmaxf(m, red[q]);
        const float e = __expf(v - m);
        float s = e;
        #pragma unroll
        for (int off = 1; off < 64; off <<= 1) s += __shfl_xor(s, off, 64);
        if (lane == 0) red[8+w] = s;
        __syncthreads();
        float sum = red[8];
        #pragma unroll
        for (int q = 1; q < 8; ++q) sum += red[8+q];
        out[(size_t)b*NSEQ + t] = e * (1.0f / sum);
    }
    __syncthreads();
    // ---- softmax(col max over 4 slices) -> p_i ----
    {
        float v = fdec(colp[t]);
        v = fmaxf(v, fdec(colp[512 + t]));
        v = fmaxf(v, fdec(colp[1024 + t]));
        v = fmaxf(v, fdec(colp[1536 + t]));
        float m = v;
        #pragma unroll
        for (int off = 1; off < 64; off <<= 1) m = fmaxf(m, __shfl_xor(m, off, 64));
        if (lane == 0) red[w] = m;
        __syncthreads();
        m = red[0];
        #pragma unroll
        for (int q = 1; q < 8; ++q) m = fmaxf(m, red[q]);
        const float e = __expf(v - m);
        float s = e;
        #pragma unroll
        for (int off = 1; off < 64; off <<= 1) s += __shfl_xor(s, off, 64);
        if (lane == 0) red[8+w] = s;
        __syncthreads();
        float sum = red[8];
        #pragma unroll
        for (int q = 1; q < 8; ++q) sum += red[8+q];
        out[(size_t)NBATCH*NSEQ + (size_t)b*NSEQ + t] = e * (1.0f / sum);
    }
}

extern "C" void kernel_launch(void* const* d_in, const int* in_sizes, int n_in,
                              void* d_out, int out_size, void* d_ws, size_t ws_size,
                              hipStream_t stream) {
    const float* u_fea = (const float*)d_in[0];
    const float* i_fea = (const float*)d_in[1];
    const float* M     = (const float*)d_in[2];
    const float* Wu    = (const float*)d_in[3];
    const float* bu    = (const float*)d_in[4];
    const float* Wi    = (const float*)d_in[5];
    const float* bi    = (const float*)d_in[6];
    float* out = (float*)d_out;
    float* ws  = (float*)d_ws;

    coatt_prep<<<64, 64, 0, stream>>>(M, Wu, bu, Wi, bi, ws);
    coatt_main<<<NBATCH, 512, LDS_BYTES, stream>>>(u_fea, i_fea, ws, out);
}